// Round 3
// baseline (444.504 us; speedup 1.0000x reference)
//
#include <hip/hip_runtime.h>
#include <cmath>

#define HID 128
#define MAXK 8          // max blocks a segment can span (len<=896 rows)
#define PIECE_F 132     // floats per piece: [m, d, pad, pad, p[128]]

typedef __attribute__((ext_vector_type(8))) short bf16x8;
typedef __attribute__((ext_vector_type(16))) float f32x16;
typedef __attribute__((ext_vector_type(4))) float f32x4;
typedef __attribute__((ext_vector_type(2))) float f32x2;
typedef __attribute__((ext_vector_type(4))) unsigned u32x4;

__device__ __forceinline__ unsigned rne_bf16_bits(float f) {
    unsigned u = __builtin_bit_cast(unsigned, f);
    return (u + 0x7FFFu + ((u >> 16) & 1u)) & 0xFFFF0000u;
}

__device__ __forceinline__ float fast_tanh(float x) {
    float e = __expf(2.0f * x);
    return 1.0f - 2.0f * __builtin_amdgcn_rcpf(e + 1.0f);
}

// Truncation split of 8 floats into bf16 hi + lo (hi+lo == f to ~2^-16 rel).
__device__ __forceinline__ void split8(const float* f, bf16x8& hi, bf16x8& lo) {
    u32x4 h, l;
    #pragma unroll
    for (int p = 0; p < 4; ++p) {
        unsigned u0 = __builtin_bit_cast(unsigned, f[2 * p]);
        unsigned u1 = __builtin_bit_cast(unsigned, f[2 * p + 1]);
        h[p] = (u0 >> 16) | (u1 & 0xFFFF0000u);
        float hf0 = __builtin_bit_cast(float, u0 & 0xFFFF0000u);
        float hf1 = __builtin_bit_cast(float, u1 & 0xFFFF0000u);
        unsigned d0 = __builtin_bit_cast(unsigned, f[2 * p] - hf0);
        unsigned d1 = __builtin_bit_cast(unsigned, f[2 * p + 1] - hf1);
        l[p] = (d0 >> 16) | (d1 & 0xFFFF0000u);
    }
    hi = __builtin_bit_cast(bf16x8, h);
    lo = __builtin_bit_cast(bf16x8, l);
}

// ---------------------------------------------------------------------------
// Prep: W -> bf16 RNE, laid out in exact A-fragment order for the fused
// kernel: frag idx id=(K8*4+t4)*32+l31 holds W[j=t4*32+l31][k=K8*8+q], q=0..7.
// ---------------------------------------------------------------------------
__global__ __launch_bounds__(256) void prep_w_frag(
    const float* __restrict__ W, short* __restrict__ whi)
{
    int id  = blockIdx.x * 256 + threadIdx.x;   // 0..2047
    int l31 = id & 31;
    int t4  = (id >> 5) & 3;
    int K8  = id >> 7;                          // 0..15
    int j   = t4 * 32 + l31;
    const float* src = W + j * HID + K8 * 8;
    short h8[8];
    #pragma unroll
    for (int q = 0; q < 8; ++q)
        h8[q] = (short)(rne_bf16_bits(src[q]) >> 16);
    *(bf16x8*)(whi + (size_t)id * 8) = *(const bf16x8*)h8;
}

// ---------------------------------------------------------------------------
// Segment starts from sorted owners (int32 or int64 storage).
// ---------------------------------------------------------------------------
__global__ void seg_start_kernel(const int* __restrict__ ow,
                                 int* __restrict__ seg_start, int N, int S)
{
    const int is64 = (ow[(size_t)N - 1] == 0) ? 1 : 0;
    long i = (long)blockIdx.x * blockDim.x + threadIdx.x;
    if (i > N) return;
    int a = (i == 0) ? -1 : ow[is64 ? (size_t)(2 * (i - 1)) : (size_t)(i - 1)];
    int b = (i == N) ? S  : ow[is64 ? (size_t)(2 * i)       : (size_t)i];
    for (int s = a + 1; s <= b; ++s) seg_start[s] = (int)i;
}

// ---------------------------------------------------------------------------
// Fused: stage X tile (128 rows) in LDS -> MFMA u -> per-piece softmax
// partials (m, d, p[128]) written per (segment, block-slot).
// X LDS layout: float (r, b8*8+w) stored at r*128 + (b8^(r&7))*8 + w.
// ---------------------------------------------------------------------------
__global__ __launch_bounds__(256, 2) void fused_kernel(
    const float* __restrict__ X, const short* __restrict__ whi,
    const float* __restrict__ bproj, const float* __restrict__ wscore,
    const int* __restrict__ ow, const int* __restrict__ seg_start,
    float* __restrict__ pieces, int N)
{
    __shared__ __align__(16) float X_lds[128 * HID];
    __shared__ float u_lds[128];
    __shared__ float w_lds[128];
    __shared__ int   ow_lds[128];
    __shared__ float bw_lds[256];
    __shared__ __align__(16) f32x4 red4[256];

    const int tid = threadIdx.x;
    const long rowBase = (long)blockIdx.x * 128;
    const int limit = (int)((N - rowBase < 128) ? (N - rowBase) : 128);

    // --- stage X: coalesced global, swizzled LDS ---
    #pragma unroll
    for (int i = 0; i < 16; ++i) {
        int r   = i * 8 + (tid >> 5);
        int c16 = tid & 31;
        long grow = rowBase + r;
        if (grow >= N) grow = N - 1;
        f32x4 v = *(const f32x4*)(X + (size_t)grow * HID + c16 * 4);
        int dst = r * HID + (((c16 >> 1) ^ (r & 7)) << 3) + ((c16 & 1) << 2);
        *(f32x4*)(&X_lds[dst]) = v;
    }
    if (tid < 128) {
        bw_lds[tid]       = bproj[tid];
        bw_lds[tid + 128] = wscore[tid];
        long rr = rowBase + tid;
        const int is64 = (ow[(size_t)N - 1] == 0) ? 1 : 0;
        ow_lds[tid] = (rr < N)
            ? ow[is64 ? (size_t)(2 * rr) : (size_t)rr] : -1;
    }
    __syncthreads();

    const int lane = tid & 63;
    const int wv   = tid >> 6;
    const int l31  = lane & 31;
    const int hig  = lane >> 5;
    const int r    = wv * 32 + l31;       // this lane's x-row (local)

    // --- MFMA: v[j][i] = sum_k W[j][k] X[i][k]; A = W-frag, B = X-frag ---
    f32x16 acc[4];
    #pragma unroll
    for (int t4 = 0; t4 < 4; ++t4)
        #pragma unroll
        for (int g = 0; g < 16; ++g) acc[t4][g] = 0.0f;

    #pragma unroll
    for (int kc = 0; kc < 8; ++kc) {
        int K8 = kc * 2 + hig;
        int lofs = r * HID + ((K8 ^ (r & 7)) << 3);
        float a8[8];
        *(f32x4*)(a8)     = *(const f32x4*)(&X_lds[lofs]);
        *(f32x4*)(a8 + 4) = *(const f32x4*)(&X_lds[lofs + 4]);
        bf16x8 xhi, xlo;
        split8(a8, xhi, xlo);
        #pragma unroll
        for (int t4 = 0; t4 < 4; ++t4) {
            bf16x8 wf = *(const bf16x8*)(whi + (size_t)(((K8 * 4 + t4) * 32 + l31)) * 8);
            acc[t4] = __builtin_amdgcn_mfma_f32_32x32x16_bf16(wf, xhi, acc[t4], 0, 0, 0);
            acc[t4] = __builtin_amdgcn_mfma_f32_32x32x16_bf16(wf, xlo, acc[t4], 0, 0, 0);
        }
    }

    // --- epilogue: u_i = sum_j wscore_j * tanh(v_ji + b_j); lane owns row i ---
    float s = 0.0f;
    #pragma unroll
    for (int t4 = 0; t4 < 4; ++t4)
        #pragma unroll
        for (int g = 0; g < 16; ++g) {
            int j = t4 * 32 + (g & 3) + ((g >> 2) << 3) + (hig << 2);
            float v = acc[t4][g] + bw_lds[j];
            s = fmaf(fast_tanh(v), bw_lds[128 + j], s);
        }
    s += __shfl_xor(s, 32, 64);
    if (hig == 0) u_lds[r] = s;
    __syncthreads();

    // --- phase 2: per-piece softmax partials from LDS X ---
    const int c4 = (tid & 31) << 2;      // col group (4 floats)
    const int rl = tid >> 5;             // row lane 0..7
    int r0 = 0;
    while (r0 < limit) {
        int sseg = ow_lds[r0];
        int r1 = r0 + 1;
        while (r1 < limit && ow_lds[r1] == sseg) ++r1;

        float m = -INFINITY;
        for (int rr = r0; rr < r1; ++rr) m = fmaxf(m, u_lds[rr]);

        if (tid >= r0 && tid < r1) w_lds[tid] = __expf(u_lds[tid] - m);
        __syncthreads();

        float d = 0.0f;
        for (int rr = r0; rr < r1; ++rr) d += w_lds[rr];

        f32x4 p = {0.0f, 0.0f, 0.0f, 0.0f};
        for (int rr = r0 + rl; rr < r1; rr += 8) {
            float w = w_lds[rr];
            int lofs = rr * HID + ((((c4 >> 3) ^ (rr & 7))) << 3) + (c4 & 7);
            f32x4 xv = *(const f32x4*)(&X_lds[lofs]);
            #pragma unroll
            for (int q = 0; q < 4; ++q) p[q] = fmaf(w, xv[q], p[q]);
        }
        red4[tid] = p;
        __syncthreads();

        if (tid < 32) {
            f32x4 q = red4[tid];
            #pragma unroll
            for (int k = 1; k < 8; ++k) {
                f32x4 o = red4[tid + 32 * k];
                q[0] += o[0]; q[1] += o[1]; q[2] += o[2]; q[3] += o[3];
            }
            int slot = (int)blockIdx.x - (seg_start[sseg] >> 7);
            slot &= (MAXK - 1);
            float* dst = pieces + ((size_t)sseg * MAXK + slot) * PIECE_F;
            if (tid == 0) { dst[0] = m; dst[1] = d; }
            *(f32x4*)(dst + 4 + (tid << 2)) = q;
        }
        __syncthreads();
        r0 = r1;
    }
}

// ---------------------------------------------------------------------------
// Fixup: merge pieces per segment -> z[s][:].
// ---------------------------------------------------------------------------
__global__ __launch_bounds__(64) void fixup_kernel(
    const float* __restrict__ pieces, const int* __restrict__ seg_start,
    float* __restrict__ z)
{
    const int s = blockIdx.x;
    const int lane = threadIdx.x;
    const int start = seg_start[s];
    const int end   = seg_start[s + 1];

    if (start >= end) {
        f32x2 zo = {0.0f, 0.0f};
        *(f32x2*)(z + (size_t)s * HID + lane * 2) = zo;
        return;
    }
    int K = ((end - 1) >> 7) - (start >> 7) + 1;
    if (K > MAXK) K = MAXK;

    const float* base0 = pieces + (size_t)s * MAXK * PIECE_F;
    float M = -INFINITY;
    for (int k = 0; k < K; ++k) M = fmaxf(M, base0[k * PIECE_F]);

    float D = 0.0f;
    f32x2 zz = {0.0f, 0.0f};
    for (int k = 0; k < K; ++k) {
        const float* b = base0 + k * PIECE_F;
        float sc = __expf(b[0] - M);
        D = fmaf(b[1], sc, D);
        f32x2 pv = *(const f32x2*)(b + 4 + lane * 2);
        zz.x = fmaf(sc, pv.x, zz.x);
        zz.y = fmaf(sc, pv.y, zz.y);
    }
    float inv = 1.0f / D;
    f32x2 zo = {zz.x * inv, zz.y * inv};
    *(f32x2*)(z + (size_t)s * HID + lane * 2) = zo;
}

// ---------------------------------------------------------------------------
extern "C" void kernel_launch(void* const* d_in, const int* in_sizes, int n_in,
                              void* d_out, int out_size, void* d_ws, size_t ws_size,
                              hipStream_t stream)
{
    const float* X   = (const float*)d_in[0];
    const int*   ow  = (const int*)  d_in[1];
    const float* W   = (const float*)d_in[2];
    const float* bp  = (const float*)d_in[3];
    const float* wsc = (const float*)d_in[4];

    const int N = in_sizes[0] / HID;
    const int S = out_size / HID;

    char* ws = (char*)d_ws;
    size_t off_seg = 0;
    size_t off_w   = (((size_t)(S + 1) * 4) + 255) & ~(size_t)255;
    size_t off_pc  = (off_w + (size_t)HID * HID * 2 + 255) & ~(size_t)255;

    int*   seg    = (int*)  (ws + off_seg);
    short* whi    = (short*)(ws + off_w);
    float* pieces = (float*)(ws + off_pc);
    float* z      = (float*)d_out;

    const int blocksB = ((N + 1) + 255) / 256;
    seg_start_kernel<<<blocksB, 256, 0, stream>>>(ow, seg, N, S);

    prep_w_frag<<<8, 256, 0, stream>>>(W, whi);

    const int blocksF = (N + 127) / 128;
    fused_kernel<<<blocksF, 256, 0, stream>>>(X, whi, bp, wsc, ow, seg, pieces, N);

    fixup_kernel<<<S, 64, 0, stream>>>(pieces, seg, z);
}

// Round 4
// 191.117 us; speedup vs baseline: 2.3258x; 2.3258x over previous
//
#include <hip/hip_runtime.h>
#include <cmath>

#define HID 128
#define MAXK 8          // max blocks a segment can span
#define PIECE_F 132     // floats per piece: [m, d, pad, pad, p[128]]

typedef __attribute__((ext_vector_type(8))) short bf16x8;
typedef __attribute__((ext_vector_type(16))) float f32x16;
typedef __attribute__((ext_vector_type(4))) float f32x4;
typedef __attribute__((ext_vector_type(2))) float f32x2;
typedef __attribute__((ext_vector_type(4))) unsigned u32x4;

__device__ __forceinline__ unsigned rne_bf16_bits(float f) {
    unsigned u = __builtin_bit_cast(unsigned, f);
    return (u + 0x7FFFu + ((u >> 16) & 1u)) & 0xFFFF0000u;
}

__device__ __forceinline__ float fast_tanh(float x) {
    float e = __expf(2.0f * x);
    return 1.0f - 2.0f * __builtin_amdgcn_rcpf(e + 1.0f);
}

// Truncation split of 8 floats into bf16 hi + lo (hi+lo == f to ~2^-16 rel).
__device__ __forceinline__ void split8(const float* f, bf16x8& hi, bf16x8& lo) {
    u32x4 h, l;
    #pragma unroll
    for (int p = 0; p < 4; ++p) {
        unsigned u0 = __builtin_bit_cast(unsigned, f[2 * p]);
        unsigned u1 = __builtin_bit_cast(unsigned, f[2 * p + 1]);
        h[p] = (u0 >> 16) | (u1 & 0xFFFF0000u);
        float hf0 = __builtin_bit_cast(float, u0 & 0xFFFF0000u);
        float hf1 = __builtin_bit_cast(float, u1 & 0xFFFF0000u);
        unsigned d0 = __builtin_bit_cast(unsigned, f[2 * p] - hf0);
        unsigned d1 = __builtin_bit_cast(unsigned, f[2 * p + 1] - hf1);
        l[p] = (d0 >> 16) | (d1 & 0xFFFF0000u);
    }
    hi = __builtin_bit_cast(bf16x8, h);
    lo = __builtin_bit_cast(bf16x8, l);
}

// ---------------------------------------------------------------------------
// Prep: W -> bf16 RNE, in exact A-fragment order:
// frag id=(K8*4+t4)*32+l31 holds W[j=t4*32+l31][k=K8*8+q], q=0..7.
// ---------------------------------------------------------------------------
__global__ __launch_bounds__(256) void prep_w_frag(
    const float* __restrict__ W, short* __restrict__ whi)
{
    int id  = blockIdx.x * 256 + threadIdx.x;   // 0..2047
    int l31 = id & 31;
    int t4  = (id >> 5) & 3;
    int K8  = id >> 7;                          // 0..15
    int j   = t4 * 32 + l31;
    const float* src = W + j * HID + K8 * 8;
    short h8[8];
    #pragma unroll
    for (int q = 0; q < 8; ++q)
        h8[q] = (short)(rne_bf16_bits(src[q]) >> 16);
    *(bf16x8*)(whi + (size_t)id * 8) = *(const bf16x8*)h8;
}

// ---------------------------------------------------------------------------
// Segment starts from sorted owners (int32/int64) + first-segment-per-block.
// ---------------------------------------------------------------------------
__global__ void seg_start_kernel(const int* __restrict__ ow,
                                 int* __restrict__ seg_start,
                                 int* __restrict__ fseg, int N, int S)
{
    const int is64 = (ow[(size_t)N - 1] == 0) ? 1 : 0;
    long i = (long)blockIdx.x * blockDim.x + threadIdx.x;
    if (i > N) return;
    int a = (i == 0) ? -1 : ow[is64 ? (size_t)(2 * (i - 1)) : (size_t)(i - 1)];
    int b = (i == N) ? S  : ow[is64 ? (size_t)(2 * i)       : (size_t)i];
    for (int s = a + 1; s <= b; ++s) seg_start[s] = (int)i;
    if (i < N && (i & 127) == 0) fseg[i >> 7] = b;   // owner of row i
}

// ---------------------------------------------------------------------------
// Fused: stage X tile (128 rows, swizzled f32) -> MFMA u -> per-piece
// (m, d, p[128]) partials, one WAVE per piece (lane-parallel reductions).
// X LDS layout: float (r, c) at r*128 + ((c>>3)^(r&7))*8 + (c&7).
// ---------------------------------------------------------------------------
__global__ __launch_bounds__(256, 2) void fused_kernel(
    const float* __restrict__ X, const short* __restrict__ whi,
    const float* __restrict__ bproj, const float* __restrict__ wscore,
    const int* __restrict__ seg_start, const int* __restrict__ fseg,
    float* __restrict__ pieces, int N, int S)
{
    __shared__ __align__(16) float X_lds[128 * HID];
    __shared__ float u_lds[128];
    __shared__ float w_lds[128];
    __shared__ float bw_lds[256];

    const int tid  = threadIdx.x;
    const int bIdx = blockIdx.x;
    const int base = bIdx * 128;
    const int limit = (N - base < 128) ? (N - base) : 128;

    const int sseg0 = fseg[bIdx];   // issued early; used in phase 2

    // --- stage X: coalesced global, swizzled LDS ---
    #pragma unroll
    for (int i = 0; i < 16; ++i) {
        int r   = i * 8 + (tid >> 5);
        int c16 = tid & 31;
        int grow = base + r;
        if (grow >= N) grow = N - 1;
        f32x4 v = *(const f32x4*)(X + (size_t)grow * HID + c16 * 4);
        int dst = r * HID + (((c16 >> 1) ^ (r & 7)) << 3) + ((c16 & 1) << 2);
        *(f32x4*)(&X_lds[dst]) = v;
    }
    if (tid < 128) {
        bw_lds[tid]       = bproj[tid];
        bw_lds[tid + 128] = wscore[tid];
    }

    const int lane = tid & 63;
    const int wv   = tid >> 6;
    const int l31  = lane & 31;
    const int hig  = lane >> 5;
    const int r    = wv * 32 + l31;       // this lane's x-row (local)

    // prefetch segment boundaries for this block's segments (one vec load)
    int svl = sseg0 + lane;
    int sv  = seg_start[(svl <= S) ? svl : S];

    __syncthreads();

    // --- MFMA: v[j][i] = sum_k W[j][k] X[i][k]; A = W-frag, B = X-frag ---
    f32x16 acc[4];
    #pragma unroll
    for (int t4 = 0; t4 < 4; ++t4)
        #pragma unroll
        for (int g = 0; g < 16; ++g) acc[t4][g] = 0.0f;

    #pragma unroll
    for (int kc = 0; kc < 8; ++kc) {
        int K8 = kc * 2 + hig;
        int lofs = r * HID + ((K8 ^ (r & 7)) << 3);
        float a8[8];
        *(f32x4*)(a8)     = *(const f32x4*)(&X_lds[lofs]);
        *(f32x4*)(a8 + 4) = *(const f32x4*)(&X_lds[lofs + 4]);
        bf16x8 xhi, xlo;
        split8(a8, xhi, xlo);
        #pragma unroll
        for (int t4 = 0; t4 < 4; ++t4) {
            bf16x8 wf = *(const bf16x8*)(whi + (size_t)(((K8 * 4 + t4) * 32 + l31)) * 8);
            acc[t4] = __builtin_amdgcn_mfma_f32_32x32x16_bf16(wf, xhi, acc[t4], 0, 0, 0);
            acc[t4] = __builtin_amdgcn_mfma_f32_32x32x16_bf16(wf, xlo, acc[t4], 0, 0, 0);
        }
    }

    // --- epilogue: u_i = sum_j wscore_j * tanh(v_ji + b_j); lane owns row i --
    float s = 0.0f;
    #pragma unroll
    for (int t4 = 0; t4 < 4; ++t4)
        #pragma unroll
        for (int g = 0; g < 16; ++g) {
            int j = t4 * 32 + (g & 3) + ((g >> 2) << 3) + (hig << 2);
            float v = acc[t4][g] + bw_lds[j];
            s = fmaf(fast_tanh(v), bw_lds[128 + j], s);
        }
    s += __shfl_xor(s, 32, 64);
    if (hig == 0) u_lds[r] = s;
    __syncthreads();

    // --- phase 2: one wave per piece; lane-parallel softmax + p accumulation -
    const int xblk = lane >> 2;           // (2*lane)>>3: 8-float block of col
    const int xoff = (2 * lane) & 7;

    for (int i = wv; ; i += 4) {
        int st, en;
        if (i < 63) {
            st = __shfl(sv, i, 64);
            en = __shfl(sv, i + 1, 64);
        } else {
            int s0 = sseg0 + i;
            st = seg_start[(s0     <= S) ? s0     : S];
            en = seg_start[(s0 + 1 <= S) ? s0 + 1 : S];
        }
        if (st >= base + limit) break;    // starts are monotone -> done
        if (en <= st) continue;           // empty segment
        int a  = st - base; if (a < 0) a = 0;
        int bb = en - base; if (bb > limit) bb = limit;
        if (a >= bb) continue;

        // max over u[a..bb) via butterfly
        float u0 = (a + lane      < bb) ? u_lds[a + lane]      : -INFINITY;
        float u1 = (a + 64 + lane < bb) ? u_lds[a + 64 + lane] : -INFINITY;
        float m = fmaxf(u0, u1);
        #pragma unroll
        for (int o = 32; o > 0; o >>= 1) m = fmaxf(m, __shfl_xor(m, o, 64));

        float e0 = (a + lane      < bb) ? __expf(u0 - m) : 0.0f;
        float e1 = (a + 64 + lane < bb) ? __expf(u1 - m) : 0.0f;
        float d = e0 + e1;
        #pragma unroll
        for (int o = 32; o > 0; o >>= 1) d += __shfl_xor(d, o, 64);

        if (a + lane      < bb) w_lds[a + lane]      = e0;
        if (a + 64 + lane < bb) w_lds[a + 64 + lane] = e1;

        // p[c] = sum_r e_r * x[r][c]; lane owns cols {2*lane, 2*lane+1}
        f32x2 p = {0.0f, 0.0f};
        for (int rr = a; rr < bb; rr += 8) {
            #pragma unroll
            for (int q = 0; q < 8; ++q) {
                int rq = rr + q;
                int rc = (rq < bb) ? rq : (bb - 1);
                float wq = w_lds[rc];
                wq = (rq < bb) ? wq : 0.0f;
                f32x2 xv = *(const f32x2*)(
                    &X_lds[rc * HID + ((xblk ^ (rc & 7)) << 3) + xoff]);
                p.x = fmaf(wq, xv.x, p.x);
                p.y = fmaf(wq, xv.y, p.y);
            }
        }

        int sseg = sseg0 + i;
        int slot = bIdx - (st >> 7);
        slot &= (MAXK - 1);
        float* dst = pieces + ((size_t)sseg * MAXK + slot) * PIECE_F;
        if (lane == 0) { dst[0] = m; dst[1] = d; }
        *(f32x2*)(dst + 4 + 2 * lane) = p;
    }
}

// ---------------------------------------------------------------------------
// Fixup: merge pieces per segment -> z[s][:].
// ---------------------------------------------------------------------------
__global__ __launch_bounds__(64) void fixup_kernel(
    const float* __restrict__ pieces, const int* __restrict__ seg_start,
    float* __restrict__ z)
{
    const int s = blockIdx.x;
    const int lane = threadIdx.x;
    const int start = seg_start[s];
    const int end   = seg_start[s + 1];

    if (start >= end) {
        f32x2 zo = {0.0f, 0.0f};
        *(f32x2*)(z + (size_t)s * HID + lane * 2) = zo;
        return;
    }
    int K = ((end - 1) >> 7) - (start >> 7) + 1;
    if (K > MAXK) K = MAXK;

    const float* base0 = pieces + (size_t)s * MAXK * PIECE_F;
    float M = -INFINITY;
    for (int k = 0; k < K; ++k) M = fmaxf(M, base0[k * PIECE_F]);

    float D = 0.0f;
    f32x2 zz = {0.0f, 0.0f};
    for (int k = 0; k < K; ++k) {
        const float* b = base0 + k * PIECE_F;
        float sc = __expf(b[0] - M);
        D = fmaf(b[1], sc, D);
        f32x2 pv = *(const f32x2*)(b + 4 + lane * 2);
        zz.x = fmaf(sc, pv.x, zz.x);
        zz.y = fmaf(sc, pv.y, zz.y);
    }
    float inv = 1.0f / D;
    f32x2 zo = {zz.x * inv, zz.y * inv};
    *(f32x2*)(z + (size_t)s * HID + lane * 2) = zo;
}

// ---------------------------------------------------------------------------
extern "C" void kernel_launch(void* const* d_in, const int* in_sizes, int n_in,
                              void* d_out, int out_size, void* d_ws, size_t ws_size,
                              hipStream_t stream)
{
    const float* X   = (const float*)d_in[0];
    const int*   ow  = (const int*)  d_in[1];
    const float* W   = (const float*)d_in[2];
    const float* bp  = (const float*)d_in[3];
    const float* wsc = (const float*)d_in[4];

    const int N = in_sizes[0] / HID;
    const int S = out_size / HID;
    const int nblocks = (N + 127) / 128;

    char* ws = (char*)d_ws;
    size_t off_seg  = 0;
    size_t off_fs   = (((size_t)(S + 1) * 4) + 255) & ~(size_t)255;
    size_t off_w    = (off_fs + (size_t)nblocks * 4 + 255) & ~(size_t)255;
    size_t off_pc   = (off_w + (size_t)HID * HID * 2 + 255) & ~(size_t)255;

    int*   seg    = (int*)  (ws + off_seg);
    int*   fsg    = (int*)  (ws + off_fs);
    short* whi    = (short*)(ws + off_w);
    float* pieces = (float*)(ws + off_pc);
    float* z      = (float*)d_out;

    const int blocksB = ((N + 1) + 255) / 256;
    seg_start_kernel<<<blocksB, 256, 0, stream>>>(ow, seg, fsg, N, S);

    prep_w_frag<<<8, 256, 0, stream>>>(W, whi);

    fused_kernel<<<nblocks, 256, 0, stream>>>(X, whi, bp, wsc, seg, fsg,
                                              pieces, N, S);

    fixup_kernel<<<S, 64, 0, stream>>>(pieces, seg, z);
}